// Round 1
// baseline (5707.452 us; speedup 1.0000x reference)
//
#include <hip/hip_runtime.h>
#include <hip/hip_bf16.h>

#define N_NODES 100000
#define N_EDGES 1600000
#define DIM 128
#define BR 32   // rows per GEMM block

// ---------------------------------------------------------------------------
// Scatter: agg_sum[dst] += feat[src]  (32 lanes of float4 per edge)
// Optionally counts degree (layer 1 only).
// ---------------------------------------------------------------------------
__global__ __launch_bounds__(256) void scatter_add_kernel(
    const float* __restrict__ feat,
    const int* __restrict__ src,
    const int* __restrict__ dst,
    float* __restrict__ agg,
    float* __restrict__ cnt,
    int num_edges, int do_cnt)
{
    long gid = (long)blockIdx.x * 256 + threadIdx.x;
    int e = (int)(gid >> 5);
    if (e >= num_edges) return;
    int c = (int)(gid & 31);

    int s = src[e];
    int d = dst[e];

    const float4 v = ((const float4*)(feat + (long)s * DIM))[c];
    float* base = agg + (long)d * DIM + c * 4;
    unsafeAtomicAdd(base + 0, v.x);
    unsafeAtomicAdd(base + 1, v.y);
    unsafeAtomicAdd(base + 2, v.z);
    unsafeAtomicAdd(base + 3, v.w);
    if (do_cnt && c == 0) unsafeAtomicAdd(cnt + d, 1.0f);
}

// ---------------------------------------------------------------------------
// Fused SAGE GEMM: out = act( (agg_sum * inv_cnt) @ Wl + xin @ Wr + b )
// Block: 256 threads, BR=32 rows. Per-thread 4x4 output tile.
// agg/x tiles staged in LDS; W streamed from cache (128 KiB resident).
// Safe in-place (out may alias xin): all reads of xin staged before writes.
// ---------------------------------------------------------------------------
__global__ __launch_bounds__(256) void sage_gemm_kernel(
    const float* __restrict__ agg,
    const float* __restrict__ cnt,
    const float* __restrict__ xin,
    const float* __restrict__ Wl,
    const float* __restrict__ Wr,
    const float* __restrict__ bias,
    float* __restrict__ out,
    int do_relu)
{
    __shared__ float aS[BR][DIM];
    __shared__ float hS[BR][DIM];

    const int tid = threadIdx.x;
    const int block_row = blockIdx.x * BR;

    // Stage: BR*DIM/4 = 1024 float4 per matrix, 256 threads -> 4 each.
    #pragma unroll
    for (int p = 0; p < 4; ++p) {
        int id = tid + p * 256;
        int r  = id >> 5;        // 0..31
        int k4 = id & 31;        // float4 index within row
        long row = block_row + r;
        float inv = 1.0f / fmaxf(cnt[row], 1.0f);
        float4 av = *(const float4*)(agg + row * DIM + k4 * 4);
        av.x *= inv; av.y *= inv; av.z *= inv; av.w *= inv;
        *(float4*)&aS[r][k4 * 4] = av;
        float4 xv = *(const float4*)(xin + row * DIM + k4 * 4);
        *(float4*)&hS[r][k4 * 4] = xv;
    }
    __syncthreads();

    const int tcol = tid & 31;   // 32 column groups
    const int trow = tid >> 5;   // 8 row groups
    const int j0 = tcol * 4;
    const int r0 = trow * 4;

    float acc[4][4];
    #pragma unroll
    for (int r = 0; r < 4; ++r)
        #pragma unroll
        for (int c = 0; c < 4; ++c) acc[r][c] = 0.0f;

    for (int k = 0; k < DIM; k += 4) {
        float4 wl[4], wr[4], a4[4], h4[4];
        #pragma unroll
        for (int i = 0; i < 4; ++i) {
            wl[i] = *(const float4*)(Wl + (long)(k + i) * DIM + j0);
            wr[i] = *(const float4*)(Wr + (long)(k + i) * DIM + j0);
        }
        #pragma unroll
        for (int r = 0; r < 4; ++r) {
            a4[r] = *(const float4*)&aS[r0 + r][k];
            h4[r] = *(const float4*)&hS[r0 + r][k];
        }
        #pragma unroll
        for (int r = 0; r < 4; ++r) {
            #pragma unroll
            for (int i = 0; i < 4; ++i) {
                float a = ((const float*)&a4[r])[i];
                float h = ((const float*)&h4[r])[i];
                acc[r][0] += a * wl[i].x + h * wr[i].x;
                acc[r][1] += a * wl[i].y + h * wr[i].y;
                acc[r][2] += a * wl[i].z + h * wr[i].z;
                acc[r][3] += a * wl[i].w + h * wr[i].w;
            }
        }
    }

    const float4 bb = *(const float4*)(bias + j0);
    #pragma unroll
    for (int r = 0; r < 4; ++r) {
        float4 o;
        o.x = acc[r][0] + bb.x;
        o.y = acc[r][1] + bb.y;
        o.z = acc[r][2] + bb.z;
        o.w = acc[r][3] + bb.w;
        if (do_relu) {
            o.x = fmaxf(o.x, 0.0f); o.y = fmaxf(o.y, 0.0f);
            o.z = fmaxf(o.z, 0.0f); o.w = fmaxf(o.w, 0.0f);
        }
        *(float4*)(out + (long)(block_row + r0 + r) * DIM + j0) = o;
    }
}

// ---------------------------------------------------------------------------
extern "C" void kernel_launch(void* const* d_in, const int* in_sizes, int n_in,
                              void* d_out, int out_size, void* d_ws, size_t ws_size,
                              hipStream_t stream)
{
    const float* x    = (const float*)d_in[0];
    const int*   ei   = (const int*)d_in[1];   // [2, E] int
    const float* W1l  = (const float*)d_in[2];
    const float* b1   = (const float*)d_in[3];
    const float* W1r  = (const float*)d_in[4];
    const float* W2l  = (const float*)d_in[5];
    const float* b2   = (const float*)d_in[6];
    const float* W2r  = (const float*)d_in[7];
    float* out = (float*)d_out;

    const int* src = ei;
    const int* dst = ei + N_EDGES;

    float* agg = (float*)d_ws;                    // N*DIM floats
    float* cnt = agg + (long)N_NODES * DIM;       // N floats

    const size_t agg_bytes = (size_t)N_NODES * DIM * sizeof(float);
    const size_t cnt_bytes = (size_t)N_NODES * sizeof(float);

    // ---- Layer 1 ----
    hipMemsetAsync(d_ws, 0, agg_bytes + cnt_bytes, stream);

    const int scatter_blocks = (N_EDGES * 32) / 256;   // 200000
    scatter_add_kernel<<<scatter_blocks, 256, 0, stream>>>(
        x, src, dst, agg, cnt, N_EDGES, 1);

    const int gemm_blocks = N_NODES / BR;              // 3125
    // h -> d_out (scratch for layer-2 input)
    sage_gemm_kernel<<<gemm_blocks, 256, 0, stream>>>(
        agg, cnt, x, W1l, W1r, b1, out, 1);

    // ---- Layer 2 ----
    hipMemsetAsync(agg, 0, agg_bytes, stream);

    scatter_add_kernel<<<scatter_blocks, 256, 0, stream>>>(
        out, src, dst, agg, cnt, N_EDGES, 0);

    // In-place: each block stages its own rows of `out` into LDS before writing.
    sage_gemm_kernel<<<gemm_blocks, 256, 0, stream>>>(
        agg, cnt, out, W2l, W2r, b2, out, 0);
}

// Round 2
// 609.266 us; speedup vs baseline: 9.3677x; 9.3677x over previous
//
#include <hip/hip_runtime.h>
#include <hip/hip_bf16.h>

#define N_NODES 100000
#define N_EDGES 1600000
#define DIM 128
#define BR 32        // rows (nodes) per fused block
#define SCAN_B 1024  // scan block size

// ---------------- workspace layout (all 4-byte elements) -------------------
// [cnts N][fill N][rowptr N+4][bsums 128][colsrc E][h N*DIM]
#define OFF_CNTS   0
#define OFF_FILL   (N_NODES)
#define OFF_ROWPTR (2 * N_NODES)
#define OFF_BSUMS  (OFF_ROWPTR + N_NODES + 4)
#define OFF_COLSRC (OFF_BSUMS + 128)
#define OFF_H      (OFF_COLSRC + N_EDGES)

// ---------------------------------------------------------------------------
// 1. Histogram of dst -> cnts
// ---------------------------------------------------------------------------
__global__ __launch_bounds__(256) void hist_kernel(
    const int* __restrict__ dst, int* __restrict__ cnts, int num_edges)
{
    int e = blockIdx.x * 256 + threadIdx.x;
    if (e < num_edges) atomicAdd(&cnts[dst[e]], 1);
}

// ---------------------------------------------------------------------------
// 2a. Per-block exclusive scan of cnts -> rowptr, block totals -> bsums
// ---------------------------------------------------------------------------
__global__ __launch_bounds__(SCAN_B) void scan1_kernel(
    const int* __restrict__ cnts, int* __restrict__ rowptr,
    int* __restrict__ bsums, int n)
{
    __shared__ int tmp[SCAN_B];
    int tid = threadIdx.x;
    int gid = blockIdx.x * SCAN_B + tid;
    int v = (gid < n) ? cnts[gid] : 0;
    tmp[tid] = v;
    __syncthreads();
    for (int off = 1; off < SCAN_B; off <<= 1) {
        int t = (tid >= off) ? tmp[tid - off] : 0;
        __syncthreads();
        tmp[tid] += t;
        __syncthreads();
    }
    if (gid < n) rowptr[gid] = tmp[tid] - v;       // exclusive
    if (tid == SCAN_B - 1) bsums[blockIdx.x] = tmp[tid];
}

// ---------------------------------------------------------------------------
// 2b. Serial exclusive scan of block sums (~98 entries)
// ---------------------------------------------------------------------------
__global__ void scan2_kernel(int* __restrict__ bsums, int nb)
{
    if (threadIdx.x == 0 && blockIdx.x == 0) {
        int acc = 0;
        for (int i = 0; i < nb; ++i) { int t = bsums[i]; bsums[i] = acc; acc += t; }
    }
}

// ---------------------------------------------------------------------------
// 2c. Add block offsets; set rowptr[N] = E
// ---------------------------------------------------------------------------
__global__ __launch_bounds__(256) void scan3_kernel(
    int* __restrict__ rowptr, const int* __restrict__ bsums, int n, int num_edges)
{
    int gid = blockIdx.x * 256 + threadIdx.x;
    if (gid < n) rowptr[gid] += bsums[gid / SCAN_B];
    if (gid == 0) rowptr[n] = num_edges;
}

// ---------------------------------------------------------------------------
// 3. Fill CSR: colsrc[rowptr[d] + ticket(d)] = src
// ---------------------------------------------------------------------------
__global__ __launch_bounds__(256) void fill_kernel(
    const int* __restrict__ src, const int* __restrict__ dst,
    const int* __restrict__ rowptr, int* __restrict__ fill,
    int* __restrict__ colsrc, int num_edges)
{
    int e = blockIdx.x * 256 + threadIdx.x;
    if (e >= num_edges) return;
    int d = dst[e];
    int pos = rowptr[d] + atomicAdd(&fill[d], 1);
    colsrc[pos] = src[e];
}

// ---------------------------------------------------------------------------
// 4. Fused SAGE layer: per block of 32 nodes,
//    gather-mean neighbors into LDS, stage self rows, then
//    out = act( agg @ Wl + self @ Wr + b ).
//    256 threads: gather as 8 groups x 32 lanes (lane c owns float4 #c);
//    GEMM as round-1 (4x4 per-thread tile).
// ---------------------------------------------------------------------------
__global__ __launch_bounds__(256) void fused_sage_kernel(
    const float* __restrict__ feat,     // gather + self source [N, DIM]
    const int* __restrict__ rowptr,
    const int* __restrict__ colsrc,
    const float* __restrict__ Wl,
    const float* __restrict__ Wr,
    const float* __restrict__ bias,
    float* __restrict__ out,
    int do_relu)
{
    __shared__ float aS[BR][DIM];   // neighbor mean
    __shared__ float hS[BR][DIM];   // self features

    const int tid = threadIdx.x;
    const int block_row = blockIdx.x * BR;
    const int c    = tid & 31;      // float4 index within a row
    const int grp  = tid >> 5;      // 8 gather groups

    // ---- gather-mean: each 32-lane group handles 4 nodes ----
    #pragma unroll
    for (int it = 0; it < 4; ++it) {
        const int nl = grp * 4 + it;            // node local 0..31
        const int n  = block_row + nl;
        const int start = rowptr[n];
        const int end   = rowptr[n + 1];
        float4 acc = make_float4(0.f, 0.f, 0.f, 0.f);
        int e = start;
        for (; e + 4 <= end; e += 4) {
            int s0 = colsrc[e + 0];
            int s1 = colsrc[e + 1];
            int s2 = colsrc[e + 2];
            int s3 = colsrc[e + 3];
            float4 v0 = *(const float4*)(feat + (long)s0 * DIM + c * 4);
            float4 v1 = *(const float4*)(feat + (long)s1 * DIM + c * 4);
            float4 v2 = *(const float4*)(feat + (long)s2 * DIM + c * 4);
            float4 v3 = *(const float4*)(feat + (long)s3 * DIM + c * 4);
            acc.x += v0.x + v1.x + v2.x + v3.x;
            acc.y += v0.y + v1.y + v2.y + v3.y;
            acc.z += v0.z + v1.z + v2.z + v3.z;
            acc.w += v0.w + v1.w + v2.w + v3.w;
        }
        for (; e < end; ++e) {
            int s = colsrc[e];
            float4 v = *(const float4*)(feat + (long)s * DIM + c * 4);
            acc.x += v.x; acc.y += v.y; acc.z += v.z; acc.w += v.w;
        }
        const float inv = 1.0f / fmaxf((float)(end - start), 1.0f);
        acc.x *= inv; acc.y *= inv; acc.z *= inv; acc.w *= inv;
        *(float4*)&aS[nl][c * 4] = acc;
    }

    // ---- stage self rows ----
    #pragma unroll
    for (int p = 0; p < 4; ++p) {
        int id = tid + p * 256;
        int r  = id >> 5;
        int k4 = id & 31;
        float4 xv = *(const float4*)(feat + (long)(block_row + r) * DIM + k4 * 4);
        *(float4*)&hS[r][k4 * 4] = xv;
    }
    __syncthreads();

    // ---- GEMM: 4x4 per-thread tile ----
    const int tcol = tid & 31;
    const int trow = tid >> 5;
    const int j0 = tcol * 4;
    const int r0 = trow * 4;

    float acc[4][4];
    #pragma unroll
    for (int r = 0; r < 4; ++r)
        #pragma unroll
        for (int q = 0; q < 4; ++q) acc[r][q] = 0.0f;

    for (int k = 0; k < DIM; k += 4) {
        float4 wl[4], wr[4], a4[4], h4[4];
        #pragma unroll
        for (int i = 0; i < 4; ++i) {
            wl[i] = *(const float4*)(Wl + (long)(k + i) * DIM + j0);
            wr[i] = *(const float4*)(Wr + (long)(k + i) * DIM + j0);
        }
        #pragma unroll
        for (int r = 0; r < 4; ++r) {
            a4[r] = *(const float4*)&aS[r0 + r][k];
            h4[r] = *(const float4*)&hS[r0 + r][k];
        }
        #pragma unroll
        for (int r = 0; r < 4; ++r) {
            #pragma unroll
            for (int i = 0; i < 4; ++i) {
                float a = ((const float*)&a4[r])[i];
                float h = ((const float*)&h4[r])[i];
                acc[r][0] += a * wl[i].x + h * wr[i].x;
                acc[r][1] += a * wl[i].y + h * wr[i].y;
                acc[r][2] += a * wl[i].z + h * wr[i].z;
                acc[r][3] += a * wl[i].w + h * wr[i].w;
            }
        }
    }

    const float4 bb = *(const float4*)(bias + j0);
    #pragma unroll
    for (int r = 0; r < 4; ++r) {
        float4 o;
        o.x = acc[r][0] + bb.x;
        o.y = acc[r][1] + bb.y;
        o.z = acc[r][2] + bb.z;
        o.w = acc[r][3] + bb.w;
        if (do_relu) {
            o.x = fmaxf(o.x, 0.0f); o.y = fmaxf(o.y, 0.0f);
            o.z = fmaxf(o.z, 0.0f); o.w = fmaxf(o.w, 0.0f);
        }
        *(float4*)(out + (long)(block_row + r0 + r) * DIM + j0) = o;
    }
}

// ---------------------------------------------------------------------------
extern "C" void kernel_launch(void* const* d_in, const int* in_sizes, int n_in,
                              void* d_out, int out_size, void* d_ws, size_t ws_size,
                              hipStream_t stream)
{
    const float* x    = (const float*)d_in[0];
    const int*   ei   = (const int*)d_in[1];   // [2, E] int32
    const float* W1l  = (const float*)d_in[2];
    const float* b1   = (const float*)d_in[3];
    const float* W1r  = (const float*)d_in[4];
    const float* W2l  = (const float*)d_in[5];
    const float* b2   = (const float*)d_in[6];
    const float* W2r  = (const float*)d_in[7];
    float* out = (float*)d_out;

    const int* src = ei;
    const int* dst = ei + N_EDGES;

    int*   wsi    = (int*)d_ws;
    int*   cnts   = wsi + OFF_CNTS;
    int*   fill   = wsi + OFF_FILL;
    int*   rowptr = wsi + OFF_ROWPTR;
    int*   bsums  = wsi + OFF_BSUMS;
    int*   colsrc = wsi + OFF_COLSRC;
    float* h      = (float*)(wsi + OFF_H);

    // zero cnts + fill in one shot (adjacent)
    hipMemsetAsync(cnts, 0, 2 * (size_t)N_NODES * sizeof(int), stream);

    const int eblocks = (N_EDGES + 255) / 256;          // 6250
    hist_kernel<<<eblocks, 256, 0, stream>>>(dst, cnts, N_EDGES);

    const int sblocks = (N_NODES + SCAN_B - 1) / SCAN_B; // 98
    scan1_kernel<<<sblocks, SCAN_B, 0, stream>>>(cnts, rowptr, bsums, N_NODES);
    scan2_kernel<<<1, 64, 0, stream>>>(bsums, sblocks);
    scan3_kernel<<<(N_NODES + 255) / 256, 256, 0, stream>>>(rowptr, bsums, N_NODES, N_EDGES);

    fill_kernel<<<eblocks, 256, 0, stream>>>(src, dst, rowptr, fill, colsrc, N_EDGES);

    const int gblocks = N_NODES / BR;                    // 3125
    // layer 1: x -> h (ws)
    fused_sage_kernel<<<gblocks, 256, 0, stream>>>(
        x, rowptr, colsrc, W1l, W1r, b1, h, 1);
    // layer 2: h -> out
    fused_sage_kernel<<<gblocks, 256, 0, stream>>>(
        h, rowptr, colsrc, W2l, W2r, b2, out, 0);
}

// Round 3
// 356.090 us; speedup vs baseline: 16.0281x; 1.7110x over previous
//
#include <hip/hip_runtime.h>
#include <hip/hip_bf16.h>

#define N_NODES 100000
#define N_EDGES 1600000
#define DIM 128
#define BR 32
#define SCAN_B 1024

typedef __attribute__((ext_vector_type(8))) short bf16x8;
typedef __attribute__((ext_vector_type(4))) float f32x4;

// ---------------- workspace layout (int units) -----------------------------
// [rowptr N+4 (doubles as cnts)][fill N][bsums 128][colsrc E][hb N*DIM/2][WB 2*16384]
#define OFF_ROWPTR 0
#define OFF_FILL   (N_NODES + 4)
#define OFF_BSUMS  (OFF_FILL + N_NODES)
#define OFF_COLSRC (OFF_BSUMS + 128)
#define OFF_HB     (OFF_COLSRC + N_EDGES)
#define OFF_WB     (OFF_HB + N_NODES * DIM / 2)

// round-to-nearest f32 -> bf16 bits
__device__ inline unsigned int f2bf(float f) {
    unsigned int u = __float_as_uint(f);
    return (u + 0x7FFFu + ((u >> 16) & 1u)) >> 16;
}

// ---------------------------------------------------------------------------
// Convert x (f32) -> xb (bf16), 8 elements/thread
// ---------------------------------------------------------------------------
__global__ __launch_bounds__(256) void conv_x_kernel(
    const float* __restrict__ x, unsigned short* __restrict__ xb)
{
    long i = (long)(blockIdx.x * 256 + threadIdx.x) * 8;
    if (i >= (long)N_NODES * DIM) return;
    float4 a = *(const float4*)(x + i);
    float4 b = *(const float4*)(x + i + 4);
    uint4 o;
    o.x = f2bf(a.x) | (f2bf(a.y) << 16);
    o.y = f2bf(a.z) | (f2bf(a.w) << 16);
    o.z = f2bf(b.x) | (f2bf(b.y) << 16);
    o.w = f2bf(b.z) | (f2bf(b.w) << 16);
    *(uint4*)(xb + i) = o;
}

// ---------------------------------------------------------------------------
// Pack weights into MFMA-B-fragment-major bf16 layout:
// WB[layer][((kk>>3)*128 + n)*8 + (kk&7)], kk = half*128 + k (Wl half 0, Wr half 1)
// ---------------------------------------------------------------------------
__global__ __launch_bounds__(256) void prep_w_kernel(
    const float* __restrict__ W1l, const float* __restrict__ W1r,
    const float* __restrict__ W2l, const float* __restrict__ W2r,
    unsigned short* __restrict__ WB)
{
    int t = blockIdx.x * 256 + threadIdx.x;
    if (t >= 2 * 2 * 128 * 128) return;
    int layer = t >> 15;
    int rest  = t & 32767;
    int half  = rest >> 14;
    int idx   = rest & 16383;
    int k = idx >> 7;
    int n = idx & 127;
    const float* W = layer ? (half ? W2r : W2l) : (half ? W1r : W1l);
    float v = W[idx];
    int kk = half * 128 + k;
    WB[layer * 32768 + (((kk >> 3) * 128 + n) << 3) + (kk & 7)] = (unsigned short)f2bf(v);
}

// ---------------------------------------------------------------------------
// CSR build
// ---------------------------------------------------------------------------
__global__ __launch_bounds__(256) void hist_kernel(
    const int* __restrict__ dst, int* __restrict__ cnts)
{
    int i = blockIdx.x * 256 + threadIdx.x;
    if (i >= N_EDGES / 4) return;
    int4 d = ((const int4*)dst)[i];
    atomicAdd(&cnts[d.x], 1);
    atomicAdd(&cnts[d.y], 1);
    atomicAdd(&cnts[d.z], 1);
    atomicAdd(&cnts[d.w], 1);
}

__global__ __launch_bounds__(SCAN_B) void scan1_kernel(
    int* __restrict__ rowcnt, int* __restrict__ bsums, int n)
{
    __shared__ int tmp[SCAN_B];
    int tid = threadIdx.x;
    int gid = blockIdx.x * SCAN_B + tid;
    int v = (gid < n) ? rowcnt[gid] : 0;
    tmp[tid] = v;
    __syncthreads();
    for (int off = 1; off < SCAN_B; off <<= 1) {
        int t = (tid >= off) ? tmp[tid - off] : 0;
        __syncthreads();
        tmp[tid] += t;
        __syncthreads();
    }
    if (gid < n) rowcnt[gid] = tmp[tid] - v;      // in-place exclusive
    if (tid == SCAN_B - 1) bsums[blockIdx.x] = tmp[tid];
}

__global__ void scan2_kernel(int* __restrict__ bsums, int nb)
{
    __shared__ int tmp[128];
    int tid = threadIdx.x;
    int v = (tid < nb) ? bsums[tid] : 0;
    tmp[tid] = v;
    __syncthreads();
    for (int off = 1; off < 128; off <<= 1) {
        int t = (tid >= off) ? tmp[tid - off] : 0;
        __syncthreads();
        tmp[tid] += t;
        __syncthreads();
    }
    if (tid < nb) bsums[tid] = tmp[tid] - v;
}

__global__ __launch_bounds__(256) void scan3_kernel(
    int* __restrict__ rowptr, const int* __restrict__ bsums, int n, int num_edges)
{
    int gid = blockIdx.x * 256 + threadIdx.x;
    if (gid < n) rowptr[gid] += bsums[gid / SCAN_B];
    if (gid == 0) rowptr[n] = num_edges;
}

__global__ __launch_bounds__(256) void fill_kernel(
    const int* __restrict__ src, const int* __restrict__ dst,
    const int* __restrict__ rowptr, int* __restrict__ fill,
    int* __restrict__ colsrc)
{
    int i = blockIdx.x * 256 + threadIdx.x;
    if (i >= N_EDGES / 4) return;
    int4 s = ((const int4*)src)[i];
    int4 d = ((const int4*)dst)[i];
    colsrc[rowptr[d.x] + atomicAdd(&fill[d.x], 1)] = s.x;
    colsrc[rowptr[d.y] + atomicAdd(&fill[d.y], 1)] = s.y;
    colsrc[rowptr[d.z] + atomicAdd(&fill[d.z], 1)] = s.z;
    colsrc[rowptr[d.w] + atomicAdd(&fill[d.w], 1)] = s.w;
}

// ---------------------------------------------------------------------------
// Fused SAGE layer (bf16):
//   gather-mean(feat) || self(feat) -> XOR-swizzled LDS [32][256] bf16
//   out = act( [agg|self] @ WB + b ) via mfma_f32_16x16x32_bf16
// 256 threads: gather = 16 groups x 16 lanes (2 nodes/group);
// GEMM = 4 waves, 2x2 (M16 x N64) tiles, K=256.
// ---------------------------------------------------------------------------
__device__ inline void addbf8(float* acc, uint4 v) {
    unsigned int u[4] = {v.x, v.y, v.z, v.w};
    #pragma unroll
    for (int i = 0; i < 4; ++i) {
        acc[2 * i]     += __uint_as_float(u[i] << 16);
        acc[2 * i + 1] += __uint_as_float(u[i] & 0xFFFF0000u);
    }
}

__global__ __launch_bounds__(256) void fused_sage_kernel(
    const unsigned short* __restrict__ feat,   // [N, DIM] bf16
    const int* __restrict__ rowptr,
    const int* __restrict__ colsrc,
    const unsigned short* __restrict__ WB,     // fragment-major [256][128] bf16
    const float* __restrict__ bias,
    unsigned short* __restrict__ outb,         // mode 1: bf16 out (relu)
    float* __restrict__ outf,                  // mode 0: f32 out
    int mode)
{
    __shared__ unsigned short catS[BR * 256];  // [row][256 k] bf16, 16B-slot XOR swizzle

    const int tid = threadIdx.x;
    const int block_row = blockIdx.x * BR;
    const int c   = tid & 15;          // 16B slot within half-row
    const int grp = tid >> 4;          // 16 gather groups

    // ---- gather-mean + self staging ----
    #pragma unroll
    for (int it = 0; it < 2; ++it) {
        const int nl = grp * 2 + it;
        const int node = block_row + nl;
        const int start = rowptr[node];
        const int end   = rowptr[node + 1];
        float acc[8];
        #pragma unroll
        for (int i = 0; i < 8; ++i) acc[i] = 0.0f;
        int e = start;
        for (; e + 4 <= end; e += 4) {
            int s0 = colsrc[e + 0];
            int s1 = colsrc[e + 1];
            int s2 = colsrc[e + 2];
            int s3 = colsrc[e + 3];
            uint4 v0 = *(const uint4*)(feat + (long)s0 * DIM + c * 8);
            uint4 v1 = *(const uint4*)(feat + (long)s1 * DIM + c * 8);
            uint4 v2 = *(const uint4*)(feat + (long)s2 * DIM + c * 8);
            uint4 v3 = *(const uint4*)(feat + (long)s3 * DIM + c * 8);
            addbf8(acc, v0); addbf8(acc, v1); addbf8(acc, v2); addbf8(acc, v3);
        }
        for (; e < end; ++e) {
            uint4 v = *(const uint4*)(feat + (long)colsrc[e] * DIM + c * 8);
            addbf8(acc, v);
        }
        const float inv = 1.0f / fmaxf((float)(end - start), 1.0f);
        uint4 pv;
        pv.x = f2bf(acc[0] * inv) | (f2bf(acc[1] * inv) << 16);
        pv.y = f2bf(acc[2] * inv) | (f2bf(acc[3] * inv) << 16);
        pv.z = f2bf(acc[4] * inv) | (f2bf(acc[5] * inv) << 16);
        pv.w = f2bf(acc[6] * inv) | (f2bf(acc[7] * inv) << 16);
        const int sw = c ^ (nl & 7);
        *(uint4*)&catS[nl * 256 + sw * 8] = pv;                       // agg: slots 0..15
        uint4 sv = *(const uint4*)(feat + (long)node * DIM + c * 8);  // self: slots 16..31
        *(uint4*)&catS[nl * 256 + 128 + sw * 8] = sv;
    }
    __syncthreads();

    // ---- MFMA GEMM: [32,256] @ [256,128] ----
    const int w    = tid >> 6;
    const int l    = tid & 63;
    const int wm   = w & 1;
    const int wn   = w >> 1;
    const int lrow = l & 15;
    const int kgrp = l >> 4;
    const int ar   = wm * 16 + lrow;   // A row (local)

    f32x4 acc4[4];
    #pragma unroll
    for (int t = 0; t < 4; ++t) acc4[t] = (f32x4){0.f, 0.f, 0.f, 0.f};

    #pragma unroll
    for (int step = 0; step < 8; ++step) {
        const int slot = step * 4 + kgrp;
        bf16x8 a = *(const bf16x8*)&catS[ar * 256 + ((slot ^ (ar & 7)) << 3)];
        #pragma unroll
        for (int t = 0; t < 4; ++t) {
            const int n = wn * 64 + t * 16 + lrow;
            bf16x8 b = *(const bf16x8*)(WB + ((slot * 128 + n) << 3));
            acc4[t] = __builtin_amdgcn_mfma_f32_16x16x32_bf16(a, b, acc4[t], 0, 0, 0);
        }
    }

    // ---- epilogue: bias (+relu+bf16 | f32) ----
    const long orow0 = block_row + wm * 16 + kgrp * 4;  // D: row=(l>>4)*4+j
    const int  cbase = wn * 64 + lrow;                  //    col=l&15
    #pragma unroll
    for (int t = 0; t < 4; ++t) {
        const int col = cbase + t * 16;
        const float bb = bias[col];
        #pragma unroll
        for (int j = 0; j < 4; ++j) {
            float v = acc4[t][j] + bb;
            const long row = orow0 + j;
            if (mode) {
                v = fmaxf(v, 0.0f);
                outb[row * DIM + col] = (unsigned short)f2bf(v);
            } else {
                outf[row * DIM + col] = v;
            }
        }
    }
}

// ---------------------------------------------------------------------------
extern "C" void kernel_launch(void* const* d_in, const int* in_sizes, int n_in,
                              void* d_out, int out_size, void* d_ws, size_t ws_size,
                              hipStream_t stream)
{
    const float* x   = (const float*)d_in[0];
    const int*   ei  = (const int*)d_in[1];
    const float* W1l = (const float*)d_in[2];
    const float* b1  = (const float*)d_in[3];
    const float* W1r = (const float*)d_in[4];
    const float* W2l = (const float*)d_in[5];
    const float* b2  = (const float*)d_in[6];
    const float* W2r = (const float*)d_in[7];
    float* out = (float*)d_out;

    const int* src = ei;
    const int* dst = ei + N_EDGES;

    int* wsi = (int*)d_ws;
    int* rowptr = wsi + OFF_ROWPTR;   // doubles as cnts
    int* fill   = wsi + OFF_FILL;
    int* bsums  = wsi + OFF_BSUMS;
    int* colsrc = wsi + OFF_COLSRC;
    unsigned short* hb = (unsigned short*)(wsi + OFF_HB);
    unsigned short* WB = (unsigned short*)(wsi + OFF_WB);

    // xb lives in d_out (dead before layer 2 overwrites d_out with f32 output)
    unsigned short* xb = (unsigned short*)d_out;

    // zero cnts + fill
    hipMemsetAsync(rowptr, 0, (size_t)(2 * N_NODES + 4) * sizeof(int), stream);

    conv_x_kernel<<<(N_NODES * DIM / 8 + 255) / 256, 256, 0, stream>>>(x, xb);
    prep_w_kernel<<<(65536 + 255) / 256, 256, 0, stream>>>(W1l, W1r, W2l, W2r, WB);

    const int e4blocks = (N_EDGES / 4 + 255) / 256;
    hist_kernel<<<e4blocks, 256, 0, stream>>>(dst, rowptr);

    const int sblocks = (N_NODES + SCAN_B - 1) / SCAN_B;   // 98
    scan1_kernel<<<sblocks, SCAN_B, 0, stream>>>(rowptr, bsums, N_NODES);
    scan2_kernel<<<1, 128, 0, stream>>>(bsums, sblocks);
    scan3_kernel<<<(N_NODES + 255) / 256, 256, 0, stream>>>(rowptr, bsums, N_NODES, N_EDGES);

    fill_kernel<<<e4blocks, 256, 0, stream>>>(src, dst, rowptr, fill, colsrc);

    const int gblocks = N_NODES / BR;   // 3125
    // layer 1: xb -> hb (bf16, relu)
    fused_sage_kernel<<<gblocks, 256, 0, stream>>>(
        xb, rowptr, colsrc, WB, b1, hb, (float*)nullptr, 1);
    // layer 2: hb -> out (f32)
    fused_sage_kernel<<<gblocks, 256, 0, stream>>>(
        hb, rowptr, colsrc, WB + 32768, b2, (unsigned short*)nullptr, out, 0);
}